// Round 1
// baseline (1235.276 us; speedup 1.0000x reference)
//
#include <hip/hip_runtime.h>
#include <math.h>

#define B_ 8
#define T_ 1024
#define C_ 768
#define H_ 8
#define D_ 96
#define QKV_LD (3 * C_)   // 2304

// ---------------------------------------------------------------------------
// GEMM: C[M,N] = A[M,K] @ B[K,N] + bias[N]
// Tiles: 64(M) x 128(N) x 16(K), 256 threads, 4x8 outputs/thread.
// As stored transposed [k][m] (padded), Bs [k][n] (padded) for float4 reads.
// ---------------------------------------------------------------------------
__global__ __launch_bounds__(256) void gemm_bias_kernel(
    const float* __restrict__ A, const float* __restrict__ Bm,
    const float* __restrict__ bias, float* __restrict__ Cm,
    int M, int N, int K)
{
  __shared__ float As[16][68];    // [k][m], padded 64->68
  __shared__ float Bs[16][132];   // [k][n], padded 128->132
  const int t    = threadIdx.x;
  const int m0   = blockIdx.y * 64;
  const int n0   = blockIdx.x * 128;
  const int rowg = t >> 4;        // 0..15  -> rows rowg*4..+3
  const int colg = t & 15;        // 0..15  -> cols colg*4..+3 and 64+colg*4..+3
  const int arow = t >> 2;        // 0..63
  const int acol = (t & 3) * 4;   // 0,4,8,12
  const int brow = t >> 5;        // 0..7
  const int bcol = (t & 31) * 4;  // 0..124

  float acc[4][8];
#pragma unroll
  for (int i = 0; i < 4; ++i)
#pragma unroll
    for (int j = 0; j < 8; ++j) acc[i][j] = 0.f;

  for (int k0 = 0; k0 < K; k0 += 16) {
    float4 a  = *(const float4*)(A  + (size_t)(m0 + arow) * K + k0 + acol);
    float4 b0 = *(const float4*)(Bm + (size_t)(k0 + brow) * N + n0 + bcol);
    float4 b1 = *(const float4*)(Bm + (size_t)(k0 + brow + 8) * N + n0 + bcol);
    __syncthreads();  // previous iteration's compute done before overwrite
    As[acol + 0][arow] = a.x;
    As[acol + 1][arow] = a.y;
    As[acol + 2][arow] = a.z;
    As[acol + 3][arow] = a.w;
    *(float4*)&Bs[brow][bcol]     = b0;
    *(float4*)&Bs[brow + 8][bcol] = b1;
    __syncthreads();
#pragma unroll
    for (int kk = 0; kk < 16; ++kk) {
      float4 av  = *(const float4*)&As[kk][rowg * 4];
      float4 bv0 = *(const float4*)&Bs[kk][colg * 4];
      float4 bv1 = *(const float4*)&Bs[kk][64 + colg * 4];
      float ar[4] = {av.x, av.y, av.z, av.w};
      float br[8] = {bv0.x, bv0.y, bv0.z, bv0.w, bv1.x, bv1.y, bv1.z, bv1.w};
#pragma unroll
      for (int i = 0; i < 4; ++i)
#pragma unroll
        for (int j = 0; j < 8; ++j)
          acc[i][j] = fmaf(ar[i], br[j], acc[i][j]);
    }
  }

  float4 bb0 = *(const float4*)(bias + n0 + colg * 4);
  float4 bb1 = *(const float4*)(bias + n0 + 64 + colg * 4);
#pragma unroll
  for (int i = 0; i < 4; ++i) {
    const int row = m0 + rowg * 4 + i;
    float4 o0, o1;
    o0.x = acc[i][0] + bb0.x; o0.y = acc[i][1] + bb0.y;
    o0.z = acc[i][2] + bb0.z; o0.w = acc[i][3] + bb0.w;
    o1.x = acc[i][4] + bb1.x; o1.y = acc[i][5] + bb1.y;
    o1.z = acc[i][6] + bb1.z; o1.w = acc[i][7] + bb1.w;
    *(float4*)(Cm + (size_t)row * N + n0 + colg * 4)      = o0;
    *(float4*)(Cm + (size_t)row * N + n0 + 64 + colg * 4) = o1;
  }
}

// ---------------------------------------------------------------------------
// Flash-style causal attention over qkv[token][3C] layout.
// Block = 256 thr = one (b,h,64-query tile). 4 lanes per query row; each lane
// owns 24 of 96 dims of Q (regs) and O (regs). Scores shuffle-reduced across
// the 4 lanes; online softmax in 16-key chunks. K/V 64x96 tiles in LDS.
// ---------------------------------------------------------------------------
__global__ __launch_bounds__(256) void attn_kernel(
    const float* __restrict__ qkv, float* __restrict__ y)
{
  __shared__ float Kt[64][96];
  __shared__ float Vt[64][96];
  const int t  = threadIdx.x;
  const int qt = blockIdx.x;      // 0..15
  const int bh = blockIdx.y;      // 0..63
  const int b  = bh >> 3;
  const int h  = bh & 7;
  const int r  = t >> 2;          // 0..63 query row in tile
  const int p  = t & 3;           // dim-chunk 0..3 (24 dims each)
  const int q0 = qt * 64;
  const int qg = q0 + r;
  const int wave_qmax = q0 + ((t >> 6) << 4) + 15;  // max qg in this wave
  const float scale = 0.10206207261596577f;         // 1/sqrt(96)

  float qreg[24], o[24];
  {
    const float* qsrc = qkv + (size_t)(b * T_ + qg) * QKV_LD + h * D_ + p * 24;
#pragma unroll
    for (int i = 0; i < 6; ++i) {
      float4 v4 = *(const float4*)(qsrc + 4 * i);
      qreg[4*i] = v4.x; qreg[4*i+1] = v4.y; qreg[4*i+2] = v4.z; qreg[4*i+3] = v4.w;
    }
  }
#pragma unroll
  for (int i = 0; i < 24; ++i) o[i] = 0.f;
  float m = -INFINITY, l = 0.f;

  for (int kt = 0; kt <= qt; ++kt) {
    const int j0 = kt * 64;
    __syncthreads();  // prior tile fully consumed
#pragma unroll
    for (int i = 0; i < 6; ++i) {
      int idx = t + 256 * i;          // 0..1535
      int row = idx / 24;
      int f4  = (idx % 24) * 4;
      const float* src = qkv + (size_t)(b * T_ + j0 + row) * QKV_LD + h * D_;
      *(float4*)&Kt[row][f4] = *(const float4*)(src + C_ + f4);
      *(float4*)&Vt[row][f4] = *(const float4*)(src + 2 * C_ + f4);
    }
    __syncthreads();

    for (int c = 0; c < 4; ++c) {
      const int jb = j0 + c * 16;
      if (jb > wave_qmax) break;      // wave-uniform branch
      float s[16];
#pragma unroll
      for (int jj = 0; jj < 16; ++jj) {
        const float* kr = &Kt[c * 16 + jj][p * 24];
        float part = 0.f;
#pragma unroll
        for (int i = 0; i < 6; ++i) {
          float4 kv = *(const float4*)(kr + 4 * i);
          part = fmaf(qreg[4*i],   kv.x, part);
          part = fmaf(qreg[4*i+1], kv.y, part);
          part = fmaf(qreg[4*i+2], kv.z, part);
          part = fmaf(qreg[4*i+3], kv.w, part);
        }
        part += __shfl_xor(part, 1, 64);
        part += __shfl_xor(part, 2, 64);
        float sj = part * scale;
        if (jb + jj > qg) sj = -INFINITY;
        s[jj] = sj;
      }
      float mt = m;
#pragma unroll
      for (int jj = 0; jj < 16; ++jj) mt = fmaxf(mt, s[jj]);
      const float alpha = __expf(m - mt);   // m=-inf first time -> 0
      l *= alpha;
#pragma unroll
      for (int i = 0; i < 24; ++i) o[i] *= alpha;
      float ls = 0.f;
#pragma unroll
      for (int jj = 0; jj < 16; ++jj) {
        float pj = __expf(s[jj] - mt);      // masked -> exp(-inf)=0
        s[jj] = pj;
        ls += pj;
      }
      l += ls;
#pragma unroll
      for (int jj = 0; jj < 16; ++jj) {
        const float pj = s[jj];
        const float* vr = &Vt[c * 16 + jj][p * 24];
#pragma unroll
        for (int i = 0; i < 6; ++i) {
          float4 vv = *(const float4*)(vr + 4 * i);
          o[4*i]   = fmaf(pj, vv.x, o[4*i]);
          o[4*i+1] = fmaf(pj, vv.y, o[4*i+1]);
          o[4*i+2] = fmaf(pj, vv.z, o[4*i+2]);
          o[4*i+3] = fmaf(pj, vv.w, o[4*i+3]);
        }
      }
      m = mt;
    }
  }

  const float inv = 1.f / l;  // l > 0: key j=qg always valid
  float* dst = y + (size_t)(b * T_ + qg) * C_ + h * D_ + p * 24;
#pragma unroll
  for (int i = 0; i < 6; ++i) {
    float4 ov;
    ov.x = o[4*i]   * inv; ov.y = o[4*i+1] * inv;
    ov.z = o[4*i+2] * inv; ov.w = o[4*i+3] * inv;
    *(float4*)(dst + 4 * i) = ov;
  }
}

// ---------------------------------------------------------------------------
extern "C" void kernel_launch(void* const* d_in, const int* in_sizes, int n_in,
                              void* d_out, int out_size, void* d_ws, size_t ws_size,
                              hipStream_t stream) {
  const float* x      = (const float*)d_in[0];   // [8,1024,768]
  const float* W_attn = (const float*)d_in[1];   // [768,2304]
  const float* b_attn = (const float*)d_in[2];   // [2304]
  const float* W_proj = (const float*)d_in[3];   // [768,768]
  const float* b_proj = (const float*)d_in[4];   // [768]
  float* out = (float*)d_out;                    // [8,1024,768]

  const int M = B_ * T_;                         // 8192
  float* qkv = (float*)d_ws;                     // [8192,2304] fp32 = 75.5 MB
  float* yws = qkv + (size_t)M * QKV_LD;         // [8192,768]  fp32 = 25.2 MB

  // 1) qkv = x @ W_attn + b_attn
  gemm_bias_kernel<<<dim3(QKV_LD / 128, M / 64), 256, 0, stream>>>(
      x, W_attn, b_attn, qkv, M, QKV_LD, C_);
  // 2) flash causal attention -> yws [B,T,C]
  attn_kernel<<<dim3(T_ / 64, B_ * H_), 256, 0, stream>>>(qkv, yws);
  // 3) out = yws @ W_proj + b_proj
  gemm_bias_kernel<<<dim3(C_ / 128, M / 64), 256, 0, stream>>>(
      yws, W_proj, b_proj, out, M, C_, C_);
}

// Round 2
// 286.783 us; speedup vs baseline: 4.3073x; 4.3073x over previous
//
#include <hip/hip_runtime.h>
#include <math.h>

#define B_ 8
#define T_ 1024
#define C_ 768
#define H_ 8
#define D_ 96
#define M_ (B_ * T_)     // 8192 tokens
#define N1_ (3 * C_)     // 2304

typedef __bf16 bf16x8 __attribute__((ext_vector_type(8)));
typedef float f32x4 __attribute__((ext_vector_type(4)));

__device__ __forceinline__ unsigned short f2bf(float f) {
  unsigned int u = __float_as_uint(f);
  u += 0x7FFF + ((u >> 16) & 1);          // round-to-nearest-even
  return (unsigned short)(u >> 16);
}

// async global->LDS, 16B per lane; LDS dest = uniform base + lane*16
__device__ __forceinline__ void load_lds16(const void* g, void* l) {
  __builtin_amdgcn_global_load_lds(
      (const __attribute__((address_space(1))) unsigned int*)g,
      (__attribute__((address_space(3))) unsigned int*)l, 16, 0, 0);
}

// ---------------------------------------------------------------------------
// fp32 -> bf16 elementwise (for x)
// ---------------------------------------------------------------------------
__global__ __launch_bounds__(256) void cvt_bf16_kernel(
    const float* __restrict__ in, unsigned short* __restrict__ out, int n) {
  int i = (blockIdx.x * 256 + threadIdx.x) * 4;
  if (i + 3 < n) {
    float4 v = *(const float4*)(in + i);
    ushort4 o;
    o.x = f2bf(v.x); o.y = f2bf(v.y); o.z = f2bf(v.z); o.w = f2bf(v.w);
    *(ushort4*)(out + i) = o;
  }
}

// ---------------------------------------------------------------------------
// W [Kd][Nd] fp32 -> WT [Nd][Kd] bf16 (so GEMM B-frags read contiguous K)
// ---------------------------------------------------------------------------
__global__ __launch_bounds__(256) void w_transpose_kernel(
    const float* __restrict__ W, unsigned short* __restrict__ WT,
    int Kd, int Nd) {
  __shared__ float Lt[32][33];
  const int r0 = blockIdx.x * 32;   // Kd
  const int c0 = blockIdx.y * 32;   // Nd
#pragma unroll
  for (int i = 0; i < 4; ++i) {
    int e = threadIdx.x + 256 * i;
    int r = e >> 5, c = e & 31;
    Lt[r][c] = W[(size_t)(r0 + r) * Nd + c0 + c];
  }
  __syncthreads();
#pragma unroll
  for (int i = 0; i < 4; ++i) {
    int e = threadIdx.x + 256 * i;
    int rr = e >> 5, cc = e & 31;
    WT[(size_t)(c0 + rr) * Kd + r0 + cc] = f2bf(Lt[cc][rr]);
  }
}

// ---------------------------------------------------------------------------
// V region of qkv [8192][2304] -> VT [bh=64][d=96][t=1024] bf16
// ---------------------------------------------------------------------------
__global__ __launch_bounds__(256) void v_transpose_kernel(
    const unsigned short* __restrict__ qkv, unsigned short* __restrict__ vt) {
  const int tid = threadIdx.x;
  const int token = blockIdx.x * 64 + (tid & 63);
  const int c = blockIdx.y * 4 + (tid >> 6);     // 0..95
  const int b = token >> 10, t = token & 1023;
  const int h = c / 12, cd = c % 12;
  const unsigned short* src =
      qkv + (size_t)token * N1_ + 2 * C_ + h * D_ + cd * 8;
  ushort4 a = *(const ushort4*)src;
  ushort4 b4 = *(const ushort4*)(src + 4);
  unsigned short v[8] = {a.x, a.y, a.z, a.w, b4.x, b4.y, b4.z, b4.w};
  size_t base = ((size_t)(b * H_ + h) * D_ + cd * 8) * T_ + t;
#pragma unroll
  for (int i = 0; i < 8; ++i) vt[base + (size_t)i * T_] = v[i];
}

// ---------------------------------------------------------------------------
// m97-style bf16 MFMA GEMM: C[M,N] = A[M,K] @ Bt[N,K]^T + bias
// 128x128 tile, BK=32, 256 thr (2x2 waves, each 64x64 = 4x4 frags of 16x16x32)
// LDS staged in fragment order via global_load_lds (lane l -> base+l*16B):
// chunk rb holds A[rb*16 + (l&15)][k: (l>>4)*8 .. +7] for the 32-wide K slab.
// ---------------------------------------------------------------------------
template <bool OUTF32>
__global__ __launch_bounds__(256) void gemm_mfma_kernel(
    const unsigned short* __restrict__ A, const unsigned short* __restrict__ Bt,
    const float* __restrict__ bias, void* __restrict__ Cout, int N, int K) {
  __shared__ __align__(16) unsigned short As[128 * 32];
  __shared__ __align__(16) unsigned short Bs[128 * 32];
  const int tid = threadIdx.x;
  const int w = tid >> 6, l = tid & 63;
  const int lm = l & 15, lq = l >> 4;
  const int m0 = blockIdx.y * 128, n0 = blockIdx.x * 128;
  const int wrb = (w >> 1) * 4;   // wave row-block base (of 16-rows)
  const int wnb = (w & 1) * 4;    // wave col-block base

  f32x4 acc[4][4];
#pragma unroll
  for (int i = 0; i < 4; ++i)
#pragma unroll
    for (int j = 0; j < 4; ++j) acc[i][j] = (f32x4){0.f, 0.f, 0.f, 0.f};

  const unsigned short* ga0 = A  + (size_t)(m0 + (2*w)   * 16 + lm) * K + lq * 8;
  const unsigned short* ga1 = A  + (size_t)(m0 + (2*w+1) * 16 + lm) * K + lq * 8;
  const unsigned short* gb0 = Bt + (size_t)(n0 + (2*w)   * 16 + lm) * K + lq * 8;
  const unsigned short* gb1 = Bt + (size_t)(n0 + (2*w+1) * 16 + lm) * K + lq * 8;

  for (int k0 = 0; k0 < K; k0 += 32) {
    __syncthreads();
    load_lds16(ga0, &As[(2*w)   * 512]);
    load_lds16(ga1, &As[(2*w+1) * 512]);
    load_lds16(gb0, &Bs[(2*w)   * 512]);
    load_lds16(gb1, &Bs[(2*w+1) * 512]);
    ga0 += 32; ga1 += 32; gb0 += 32; gb1 += 32;
    __syncthreads();
    bf16x8 af[4], bfr[4];
#pragma unroll
    for (int mi = 0; mi < 4; ++mi)
      af[mi] = *(const bf16x8*)&As[(wrb + mi) * 512 + l * 8];
#pragma unroll
    for (int ni = 0; ni < 4; ++ni)
      bfr[ni] = *(const bf16x8*)&Bs[(wnb + ni) * 512 + l * 8];
#pragma unroll
    for (int mi = 0; mi < 4; ++mi)
#pragma unroll
      for (int ni = 0; ni < 4; ++ni)
        acc[mi][ni] = __builtin_amdgcn_mfma_f32_16x16x32_bf16(
            af[mi], bfr[ni], acc[mi][ni], 0, 0, 0);
  }

#pragma unroll
  for (int mi = 0; mi < 4; ++mi) {
    const int row = m0 + (wrb + mi) * 16 + lq * 4;
#pragma unroll
    for (int ni = 0; ni < 4; ++ni) {
      const int col = n0 + (wnb + ni) * 16 + lm;
      const float bv = bias[col];
#pragma unroll
      for (int r = 0; r < 4; ++r) {
        float v = acc[mi][ni][r] + bv;
        if (OUTF32)
          ((float*)Cout)[(size_t)(row + r) * N + col] = v;
        else
          ((unsigned short*)Cout)[(size_t)(row + r) * N + col] = f2bf(v);
      }
    }
  }
}

// ---------------------------------------------------------------------------
// Flash causal attention, bf16 MFMA 16x16x32.
// Block = 256 thr = (b, h, 64-query tile); wave w owns queries q0+16w..+15.
// Per 64-key tile: QK^T (12 MFMA/wave), online softmax fp32 in C-layout,
// P -> LDS (padded) -> A-frags, PV (12 MFMA/wave) from VT fragment chunks.
// ---------------------------------------------------------------------------
__global__ __launch_bounds__(256) void attn_mfma_kernel(
    const unsigned short* __restrict__ qkv,  // [8192][2304]
    const unsigned short* __restrict__ vt,   // [64][96][1024]
    unsigned short* __restrict__ y) {        // [8192][768]
  __shared__ __align__(16) unsigned short Ks[12 * 512];  // ck = kc*4+nb
  __shared__ __align__(16) unsigned short Vs[12 * 512];  // cv = db*2+vc
  __shared__ __align__(16) unsigned short Pt[4][16][72]; // pad 64->72

  const int tid = threadIdx.x;
  const int w = tid >> 6, l = tid & 63;
  const int lm = l & 15, lq = l >> 4;
  const int qt = blockIdx.x, bh = blockIdx.y;
  const int b = bh >> 3, h = bh & 7;
  const int q0 = qt * 64;
  const size_t bT = (size_t)b * T_;
  const float scale = 0.10206207261596577f;  // 1/sqrt(96)

  bf16x8 qf[3];
  {
    const unsigned short* qp =
        qkv + (bT + q0 + w * 16 + lm) * N1_ + h * D_ + lq * 8;
    qf[0] = *(const bf16x8*)(qp);
    qf[1] = *(const bf16x8*)(qp + 32);
    qf[2] = *(const bf16x8*)(qp + 64);
  }
  f32x4 o[6];
#pragma unroll
  for (int i = 0; i < 6; ++i) o[i] = (f32x4){0.f, 0.f, 0.f, 0.f};
  float mrow[4] = {-INFINITY, -INFINITY, -INFINITY, -INFINITY};
  float lrow[4] = {0.f, 0.f, 0.f, 0.f};

  for (int jt = 0; jt <= qt; ++jt) {
    const int j0 = jt * 64;
    __syncthreads();  // prior tile's LDS fully consumed
#pragma unroll
    for (int i = 0; i < 6; ++i) {
      const int c = w * 6 + i;
      if (c < 12) {  // K chunk: B-frag layout for QK^T
        const int kc = c >> 2, nb = c & 3;
        const unsigned short* g = qkv + (bT + j0 + nb * 16 + lm) * N1_ +
                                  C_ + h * D_ + kc * 32 + lq * 8;
        load_lds16(g, &Ks[c * 512]);
      } else {       // V chunk: B-frag layout for PV (from VT)
        const int cv = c - 12;
        const int db = cv >> 1, vc = cv & 1;
        const unsigned short* g = vt + ((size_t)bh * D_ + db * 16 + lm) * T_ +
                                  j0 + vc * 32 + lq * 8;
        load_lds16(g, &Vs[cv * 512]);
      }
    }
    __syncthreads();

    // S = Q K^T : C-layout col(key)=lm, row(query)=lq*4+r
    f32x4 s[4];
#pragma unroll
    for (int nb = 0; nb < 4; ++nb) {
      f32x4 a = (f32x4){0.f, 0.f, 0.f, 0.f};
#pragma unroll
      for (int kc = 0; kc < 3; ++kc) {
        bf16x8 kf = *(const bf16x8*)&Ks[(kc * 4 + nb) * 512 + l * 8];
        a = __builtin_amdgcn_mfma_f32_16x16x32_bf16(qf[kc], kf, a, 0, 0, 0);
      }
      s[nb] = a;
    }

    const bool diag = (jt == qt);
    float sv[4][4];
#pragma unroll
    for (int nb = 0; nb < 4; ++nb)
#pragma unroll
      for (int r = 0; r < 4; ++r) {
        float v = s[nb][r] * scale;
        if (diag && (nb * 16 + lm > w * 16 + lq * 4 + r)) v = -INFINITY;
        sv[nb][r] = v;
      }

    float mt[4];
#pragma unroll
    for (int r = 0; r < 4; ++r)
      mt[r] = fmaxf(fmaxf(fmaxf(sv[0][r], sv[1][r]), fmaxf(sv[2][r], sv[3][r])),
                    mrow[r]);
#pragma unroll
    for (int mask = 1; mask <= 8; mask <<= 1)
#pragma unroll
      for (int r = 0; r < 4; ++r)
        mt[r] = fmaxf(mt[r], __shfl_xor(mt[r], mask, 64));

    float alpha[4], rs[4];
#pragma unroll
    for (int r = 0; r < 4; ++r) {
      alpha[r] = __expf(mrow[r] - mt[r]);  // first tile: exp(-inf)=0
      mrow[r] = mt[r];
      rs[r] = 0.f;
    }
#pragma unroll
    for (int nb = 0; nb < 4; ++nb)
#pragma unroll
      for (int r = 0; r < 4; ++r) {
        float p = __expf(sv[nb][r] - mt[r]);  // masked -> 0
        rs[r] += p;
        Pt[w][lq * 4 + r][nb * 16 + lm] = f2bf(p);
      }
#pragma unroll
    for (int mask = 1; mask <= 8; mask <<= 1)
#pragma unroll
      for (int r = 0; r < 4; ++r) rs[r] += __shfl_xor(rs[r], mask, 64);
#pragma unroll
    for (int r = 0; r < 4; ++r) lrow[r] = lrow[r] * alpha[r] + rs[r];
#pragma unroll
    for (int db = 0; db < 6; ++db)
#pragma unroll
      for (int r = 0; r < 4; ++r) o[db][r] *= alpha[r];

    // PV: P as A-frag (round-trip through Pt), V-frags from Vs
    bf16x8 pf[2];
    pf[0] = *(const bf16x8*)&Pt[w][lm][lq * 8];
    pf[1] = *(const bf16x8*)&Pt[w][lm][32 + lq * 8];
#pragma unroll
    for (int db = 0; db < 6; ++db)
#pragma unroll
      for (int vc = 0; vc < 2; ++vc) {
        bf16x8 vf = *(const bf16x8*)&Vs[(db * 2 + vc) * 512 + l * 8];
        o[db] = __builtin_amdgcn_mfma_f32_16x16x32_bf16(pf[vc], vf, o[db], 0, 0, 0);
      }
  }

#pragma unroll
  for (int r = 0; r < 4; ++r) {
    const float inv = 1.f / lrow[r];
    const size_t row = bT + q0 + w * 16 + lq * 4 + r;
#pragma unroll
    for (int db = 0; db < 6; ++db)
      y[row * C_ + h * D_ + db * 16 + lm] = f2bf(o[db][r] * inv);
  }
}

// ---------------------------------------------------------------------------
extern "C" void kernel_launch(void* const* d_in, const int* in_sizes, int n_in,
                              void* d_out, int out_size, void* d_ws, size_t ws_size,
                              hipStream_t stream) {
  const float* x      = (const float*)d_in[0];
  const float* W_attn = (const float*)d_in[1];
  const float* b_attn = (const float*)d_in[2];
  const float* W_proj = (const float*)d_in[3];
  const float* b_proj = (const float*)d_in[4];
  float* out = (float*)d_out;

  char* ws = (char*)d_ws;
  unsigned short* xb  = (unsigned short*)(ws);                    // 12.58 MB
  unsigned short* WaT = (unsigned short*)(ws + 12582912);         //  3.54 MB
  unsigned short* WpT = (unsigned short*)(ws + 16121856);         //  1.18 MB
  unsigned short* qkv = (unsigned short*)(ws + 17301504);         // 37.75 MB
  unsigned short* vt  = (unsigned short*)(ws + 55050240);         // 12.58 MB
  unsigned short* yb  = (unsigned short*)(ws + 67633152);         // 12.58 MB

  // prep: casts + weight transposes
  cvt_bf16_kernel<<<(M_ * C_) / 1024, 256, 0, stream>>>(x, xb, M_ * C_);
  w_transpose_kernel<<<dim3(C_ / 32, N1_ / 32), 256, 0, stream>>>(W_attn, WaT, C_, N1_);
  w_transpose_kernel<<<dim3(C_ / 32, C_ / 32), 256, 0, stream>>>(W_proj, WpT, C_, C_);

  // qkv = x @ W_attn + b_attn   (bf16 out)
  gemm_mfma_kernel<false><<<dim3(N1_ / 128, M_ / 128), 256, 0, stream>>>(
      xb, WaT, b_attn, qkv, N1_, C_);
  // V -> VT [bh][d][t]
  v_transpose_kernel<<<dim3(M_ / 64, 24), 256, 0, stream>>>(qkv, vt);
  // flash attention -> yb bf16
  attn_mfma_kernel<<<dim3(T_ / 64, B_ * H_), 256, 0, stream>>>(qkv, vt, yb);
  // out = yb @ W_proj + b_proj  (fp32 out)
  gemm_mfma_kernel<true><<<dim3(C_ / 128, M_ / 128), 256, 0, stream>>>(
      yb, WpT, b_proj, out, C_, C_);
}

// Round 3
// 233.454 us; speedup vs baseline: 5.2913x; 1.2284x over previous
//
#include <hip/hip_runtime.h>
#include <math.h>

#define B_ 8
#define T_ 1024
#define C_ 768
#define H_ 8
#define D_ 96
#define M_ (B_ * T_)     // 8192 tokens
#define N1_ (3 * C_)     // 2304

typedef __bf16 bf16x8 __attribute__((ext_vector_type(8)));
typedef float f32x4 __attribute__((ext_vector_type(4)));

__device__ __forceinline__ unsigned short f2bf(float f) {
  unsigned int u = __float_as_uint(f);
  u += 0x7FFF + ((u >> 16) & 1);          // round-to-nearest-even
  return (unsigned short)(u >> 16);
}

// async global->LDS, 16B per lane; LDS dest = uniform base + lane*16
__device__ __forceinline__ void load_lds16(const void* g, void* l) {
  __builtin_amdgcn_global_load_lds(
      (const __attribute__((address_space(1))) unsigned int*)g,
      (__attribute__((address_space(3))) unsigned int*)l, 16, 0, 0);
}

// ---------------------------------------------------------------------------
// fp32 -> bf16 elementwise (for x)
// ---------------------------------------------------------------------------
__global__ __launch_bounds__(256) void cvt_bf16_kernel(
    const float* __restrict__ in, unsigned short* __restrict__ out, int n) {
  int i = (blockIdx.x * 256 + threadIdx.x) * 4;
  if (i + 3 < n) {
    float4 v = *(const float4*)(in + i);
    ushort4 o;
    o.x = f2bf(v.x); o.y = f2bf(v.y); o.z = f2bf(v.z); o.w = f2bf(v.w);
    *(ushort4*)(out + i) = o;
  }
}

// ---------------------------------------------------------------------------
// W [Kd][Nd] fp32 -> WT [Nd][Kd] bf16
// ---------------------------------------------------------------------------
__global__ __launch_bounds__(256) void w_transpose_kernel(
    const float* __restrict__ W, unsigned short* __restrict__ WT,
    int Kd, int Nd) {
  __shared__ float Lt[32][33];
  const int r0 = blockIdx.x * 32;   // Kd
  const int c0 = blockIdx.y * 32;   // Nd
#pragma unroll
  for (int i = 0; i < 4; ++i) {
    int e = threadIdx.x + 256 * i;
    int r = e >> 5, c = e & 31;
    Lt[r][c] = W[(size_t)(r0 + r) * Nd + c0 + c];
  }
  __syncthreads();
#pragma unroll
  for (int i = 0; i < 4; ++i) {
    int e = threadIdx.x + 256 * i;
    int rr = e >> 5, cc = e & 31;
    WT[(size_t)(c0 + rr) * Kd + r0 + cc] = f2bf(Lt[cc][rr]);
  }
}

// ---------------------------------------------------------------------------
// V region of qkv [8192][2304] -> VT [bh=64][d=96][t=1024] bf16
// ---------------------------------------------------------------------------
__global__ __launch_bounds__(256) void v_transpose_kernel(
    const unsigned short* __restrict__ qkv, unsigned short* __restrict__ vt) {
  const int tid = threadIdx.x;
  const int token = blockIdx.x * 64 + (tid & 63);
  const int c = blockIdx.y * 4 + (tid >> 6);     // 0..95
  const int b = token >> 10, t = token & 1023;
  const int h = c / 12, cd = c % 12;
  const unsigned short* src =
      qkv + (size_t)token * N1_ + 2 * C_ + h * D_ + cd * 8;
  ushort4 a = *(const ushort4*)src;
  ushort4 b4 = *(const ushort4*)(src + 4);
  unsigned short v[8] = {a.x, a.y, a.z, a.w, b4.x, b4.y, b4.z, b4.w};
  size_t base = ((size_t)(b * H_ + h) * D_ + cd * 8) * T_ + t;
#pragma unroll
  for (int i = 0; i < 8; ++i) vt[base + (size_t)i * T_] = v[i];
}

// ---------------------------------------------------------------------------
// bf16 MFMA GEMM: C[M,N] = A[M,K] @ Bt[N,K]^T + bias, optional col-range scale
// 128x128 tile, BK=64, 256 thr (2x2 waves, each 64x64 = 4x4 frags 16x16x32).
// LDS in fragment order: slab s chunk c lane l = A[s*16+(l&15)][c*32+(l>>4)*8].
// ---------------------------------------------------------------------------
template <bool OUTF32>
__global__ __launch_bounds__(256) void gemm_mfma_kernel(
    const unsigned short* __restrict__ A, const unsigned short* __restrict__ Bt,
    const float* __restrict__ bias, void* __restrict__ Cout, int N, int K,
    int sc_lim, float sc) {
  __shared__ __align__(16) unsigned short As[128 * 64];  // 16 KB
  __shared__ __align__(16) unsigned short Bs[128 * 64];  // 16 KB
  const int tid = threadIdx.x;
  const int w = tid >> 6, l = tid & 63;
  const int lm = l & 15, lq = l >> 4;
  const int m0 = blockIdx.y * 128, n0 = blockIdx.x * 128;
  const int wrb = (w >> 1) * 4;
  const int wnb = (w & 1) * 4;

  f32x4 acc[4][4];
#pragma unroll
  for (int i = 0; i < 4; ++i)
#pragma unroll
    for (int j = 0; j < 4; ++j) acc[i][j] = (f32x4){0.f, 0.f, 0.f, 0.f};

  // 8 staging pointers: [A/B][slab 0/1][chunk 0/1]
  const unsigned short* gA[2][2];
  const unsigned short* gB[2][2];
#pragma unroll
  for (int s = 0; s < 2; ++s)
#pragma unroll
    for (int c = 0; c < 2; ++c) {
      gA[s][c] = A  + (size_t)(m0 + (2 * w + s) * 16 + lm) * K + c * 32 + lq * 8;
      gB[s][c] = Bt + (size_t)(n0 + (2 * w + s) * 16 + lm) * K + c * 32 + lq * 8;
    }

  for (int k0 = 0; k0 < K; k0 += 64) {
    __syncthreads();
#pragma unroll
    for (int s = 0; s < 2; ++s)
#pragma unroll
      for (int c = 0; c < 2; ++c) {
        load_lds16(gA[s][c], &As[(2 * w + s) * 1024 + c * 512]);
        load_lds16(gB[s][c], &Bs[(2 * w + s) * 1024 + c * 512]);
        gA[s][c] += 64; gB[s][c] += 64;
      }
    __syncthreads();
#pragma unroll
    for (int kk = 0; kk < 2; ++kk) {
      bf16x8 af[4], bfr[4];
#pragma unroll
      for (int mi = 0; mi < 4; ++mi)
        af[mi] = *(const bf16x8*)&As[(wrb + mi) * 1024 + kk * 512 + l * 8];
#pragma unroll
      for (int ni = 0; ni < 4; ++ni)
        bfr[ni] = *(const bf16x8*)&Bs[(wnb + ni) * 1024 + kk * 512 + l * 8];
#pragma unroll
      for (int mi = 0; mi < 4; ++mi)
#pragma unroll
        for (int ni = 0; ni < 4; ++ni)
          acc[mi][ni] = __builtin_amdgcn_mfma_f32_16x16x32_bf16(
              af[mi], bfr[ni], acc[mi][ni], 0, 0, 0);
    }
  }

#pragma unroll
  for (int mi = 0; mi < 4; ++mi) {
    const int row = m0 + (wrb + mi) * 16 + lq * 4;
#pragma unroll
    for (int ni = 0; ni < 4; ++ni) {
      const int col = n0 + (wnb + ni) * 16 + lm;
      const float bv = bias[col];
      const float mul = (col < sc_lim) ? sc : 1.f;
#pragma unroll
      for (int r = 0; r < 4; ++r) {
        float v = (acc[mi][ni][r] + bv) * mul;
        if (OUTF32)
          ((float*)Cout)[(size_t)(row + r) * N + col] = v;
        else
          ((unsigned short*)Cout)[(size_t)(row + r) * N + col] = f2bf(v);
      }
    }
  }
}

// ---------------------------------------------------------------------------
// Flash causal attention, bf16 MFMA, max-free softmax (scores pre-scaled in
// qkv's Q, bounded << 88 so exp() cannot overflow). Row-sum l computed by an
// extra MFMA with an all-ones B fragment. Block = (pair of q-tiles qt,15-qt)
// x (b,h): every block does exactly 17 key-tiles -> perfect balance.
// ---------------------------------------------------------------------------
__global__ __launch_bounds__(256) void attn_mfma_kernel(
    const unsigned short* __restrict__ qkv,  // [8192][2304], Q pre-scaled
    const unsigned short* __restrict__ vt,   // [64][96][1024]
    unsigned short* __restrict__ y) {        // [8192][768]
  __shared__ __align__(16) unsigned short Ks[12 * 512];  // ck = kc*4+nb
  __shared__ __align__(16) unsigned short Vs[12 * 512];  // cv = db*2+vc
  __shared__ __align__(16) unsigned short Pt[4][16][72]; // pad 64->72

  const int tid = threadIdx.x;
  const int w = tid >> 6, l = tid & 63;
  const int lm = l & 15, lq = l >> 4;
  const int pi = blockIdx.x, bh = blockIdx.y;
  const int b = bh >> 3, h = bh & 7;
  const size_t bT = (size_t)b * T_;

  bf16x8 onef;
#pragma unroll
  for (int i = 0; i < 8; ++i) onef[i] = (__bf16)1.0f;

  for (int half = 0; half < 2; ++half) {
    const int qt = half ? (15 - pi) : pi;
    const int q0 = qt * 64;

    bf16x8 qf[3];
    {
      const unsigned short* qp =
          qkv + (bT + q0 + w * 16 + lm) * N1_ + h * D_ + lq * 8;
      qf[0] = *(const bf16x8*)(qp);
      qf[1] = *(const bf16x8*)(qp + 32);
      qf[2] = *(const bf16x8*)(qp + 64);
    }
    f32x4 o[7];  // 6 dim-blocks + l accumulator
#pragma unroll
    for (int i = 0; i < 7; ++i) o[i] = (f32x4){0.f, 0.f, 0.f, 0.f};

    for (int jt = 0; jt <= qt; ++jt) {
      const int j0 = jt * 64;
      __syncthreads();  // prior tile's LDS fully consumed
#pragma unroll
      for (int i = 0; i < 6; ++i) {
        const int c = w * 6 + i;
        if (c < 12) {  // K chunk: B-frag layout for QK^T
          const int kc = c >> 2, nb = c & 3;
          const unsigned short* g = qkv + (bT + j0 + nb * 16 + lm) * N1_ +
                                    C_ + h * D_ + kc * 32 + lq * 8;
          load_lds16(g, &Ks[c * 512]);
        } else {       // V chunk: B-frag layout for PV (from VT)
          const int cv = c - 12;
          const int db = cv >> 1, vc = cv & 1;
          const unsigned short* g = vt + ((size_t)bh * D_ + db * 16 + lm) * T_ +
                                    j0 + vc * 32 + lq * 8;
          load_lds16(g, &Vs[cv * 512]);
        }
      }
      __syncthreads();

      const bool diag = (jt == qt);
#pragma unroll
      for (int nb = 0; nb < 4; ++nb) {
        if (diag && nb > w) {  // wave-uniform: block fully masked
#pragma unroll
          for (int r = 0; r < 4; ++r)
            Pt[w][lq * 4 + r][nb * 16 + lm] = 0;
          continue;
        }
        f32x4 a = (f32x4){0.f, 0.f, 0.f, 0.f};
#pragma unroll
        for (int kc = 0; kc < 3; ++kc) {
          bf16x8 kf = *(const bf16x8*)&Ks[(kc * 4 + nb) * 512 + l * 8];
          a = __builtin_amdgcn_mfma_f32_16x16x32_bf16(qf[kc], kf, a, 0, 0, 0);
        }
#pragma unroll
        for (int r = 0; r < 4; ++r) {
          float s = a[r];
          if (diag && (nb * 16 + lm > w * 16 + lq * 4 + r)) s = -INFINITY;
          Pt[w][lq * 4 + r][nb * 16 + lm] = f2bf(__expf(s));
        }
      }

      // PV: P as A-frag (per-wave LDS round trip), V-frags + ones-frag
      bf16x8 pf0 = *(const bf16x8*)&Pt[w][lm][lq * 8];
      bf16x8 pf1 = *(const bf16x8*)&Pt[w][lm][32 + lq * 8];
#pragma unroll
      for (int db = 0; db < 6; ++db) {
        bf16x8 vf0 = *(const bf16x8*)&Vs[(db * 2 + 0) * 512 + l * 8];
        bf16x8 vf1 = *(const bf16x8*)&Vs[(db * 2 + 1) * 512 + l * 8];
        o[db] = __builtin_amdgcn_mfma_f32_16x16x32_bf16(pf0, vf0, o[db], 0, 0, 0);
        o[db] = __builtin_amdgcn_mfma_f32_16x16x32_bf16(pf1, vf1, o[db], 0, 0, 0);
      }
      o[6] = __builtin_amdgcn_mfma_f32_16x16x32_bf16(pf0, onef, o[6], 0, 0, 0);
      o[6] = __builtin_amdgcn_mfma_f32_16x16x32_bf16(pf1, onef, o[6], 0, 0, 0);
    }

#pragma unroll
    for (int r = 0; r < 4; ++r) {
      const float inv = 1.f / o[6][r];
      const size_t row = bT + q0 + w * 16 + lq * 4 + r;
#pragma unroll
      for (int db = 0; db < 6; ++db)
        y[row * C_ + h * D_ + db * 16 + lm] = f2bf(o[db][r] * inv);
    }
  }
}

// ---------------------------------------------------------------------------
extern "C" void kernel_launch(void* const* d_in, const int* in_sizes, int n_in,
                              void* d_out, int out_size, void* d_ws, size_t ws_size,
                              hipStream_t stream) {
  const float* x      = (const float*)d_in[0];
  const float* W_attn = (const float*)d_in[1];
  const float* b_attn = (const float*)d_in[2];
  const float* W_proj = (const float*)d_in[3];
  const float* b_proj = (const float*)d_in[4];
  float* out = (float*)d_out;

  char* ws = (char*)d_ws;
  unsigned short* xb  = (unsigned short*)(ws);                    // 12.58 MB
  unsigned short* WaT = (unsigned short*)(ws + 12582912);         //  3.54 MB
  unsigned short* WpT = (unsigned short*)(ws + 16121856);         //  1.18 MB
  unsigned short* qkv = (unsigned short*)(ws + 17301504);         // 37.75 MB
  unsigned short* vt  = (unsigned short*)(ws + 55050240);         // 12.58 MB
  unsigned short* yb  = (unsigned short*)(ws + 67633152);         // 12.58 MB

  const float qscale = 0.10206207261596577f;  // 1/sqrt(96)

  cvt_bf16_kernel<<<(M_ * C_) / 1024, 256, 0, stream>>>(x, xb, M_ * C_);
  w_transpose_kernel<<<dim3(C_ / 32, N1_ / 32), 256, 0, stream>>>(W_attn, WaT, C_, N1_);
  w_transpose_kernel<<<dim3(C_ / 32, C_ / 32), 256, 0, stream>>>(W_proj, WpT, C_, C_);

  // qkv = x @ W_attn + b_attn; Q columns (<768) pre-scaled by 1/sqrt(D) in fp32
  gemm_mfma_kernel<false><<<dim3(N1_ / 128, M_ / 128), 256, 0, stream>>>(
      xb, WaT, b_attn, qkv, N1_, C_, C_, qscale);
  v_transpose_kernel<<<dim3(M_ / 64, 24), 256, 0, stream>>>(qkv, vt);
  attn_mfma_kernel<<<dim3(8, B_ * H_), 256, 0, stream>>>(qkv, vt, yb);
  gemm_mfma_kernel<true><<<dim3(C_ / 128, M_ / 128), 256, 0, stream>>>(
      yb, WpT, b_proj, out, C_, C_, 0, 1.f);
}